// Round 8
// baseline (517.494 us; speedup 1.0000x reference)
//
#include <hip/hip_runtime.h>

// SegmentedAttention round 8.
// attn_fused: 8 waves = 2 key-parity groups x 4 waves; each wave 32 q-rows.
// Both groups compute every iteration on separate KV buffer pairs -> 16
// waves/CU with 32-row LDS amortization. Partial (O,l) combined via LDS
// exchange (no online max -> partials just add). PV in two 32-key ch-phases
// (Ps only 32 cols). LDS 57.3KB -> 2 blocks/CU. launch_bounds(512,4).
// Rest identical to r7.

constexpr int SEQ    = 2048;
constexpr int DMODEL = 1024;
constexpr int NH     = 16;
constexpr int DHEAD  = 64;
constexpr int BHT    = 32;
constexpr int NG     = 204;
constexpr int NGPAD  = 256;
constexpr float LNEPS = 1e-5f;

typedef __attribute__((ext_vector_type(8))) short short8;
typedef __attribute__((ext_vector_type(4))) short short4v;
typedef __attribute__((ext_vector_type(4))) float f32x4;

__device__ __forceinline__ unsigned short f2bf(float f) {
    unsigned int u = __float_as_uint(f);
    u += 0x7FFFu + ((u >> 16) & 1u);
    return (unsigned short)(u >> 16);
}
__device__ __forceinline__ float bf2f(unsigned short b) {
    return __uint_as_float(((unsigned int)b) << 16);
}

// ---------------------------------------------------------------------------
__global__ __launch_bounds__(256)
void prep_k(const float* __restrict__ x,
            const float* __restrict__ Wq, const float* __restrict__ Wv,
            const float* __restrict__ Wo, const float* __restrict__ Wk,
            const float* __restrict__ Wg,
            unsigned short* __restrict__ xh, unsigned short* __restrict__ xl,
            unsigned short* __restrict__ Wqt, unsigned short* __restrict__ Wvt,
            unsigned short* __restrict__ Wot, unsigned short* __restrict__ Wkh,
            unsigned short* __restrict__ Wkl, unsigned short* __restrict__ Wgt)
{
    const int bid = blockIdx.x;
    const int tid = threadIdx.x;

    if (bid < 2048) {
        int i = (bid * 256 + tid) << 3;
        short8 h, l;
#pragma unroll
        for (int j = 0; j < 8; ++j) {
            float v = x[i + j];
            unsigned short hb = f2bf(v);
            h[j] = (short)hb;
            l[j] = (short)f2bf(v - bf2f(hb));
        }
        *(short8*)(xh + i) = h;
        *(short8*)(xl + i) = l;
        return;
    }
    if (bid == 3072) {
#pragma unroll
        for (int i = 0; i < 32; ++i) {
            int o = tid * 32 + i;
            int dg = o >> 7, jj = o & 127;
            Wgt[o] = f2bf(Wg[jj * 64 + dg]);
        }
        return;
    }

    __shared__ float tile[64][68];
    const int sub = bid - 2048;
    const int which = sub >> 8;             // 0:Wq 1:Wv 2:Wo 3:Wk
    const int b = sub & 255;
    const int n0 = (b & 15) * 64, k0 = (b >> 4) * 64;
    const float* W = (which == 0) ? Wq : (which == 1) ? Wv : (which == 2) ? Wo : Wk;
    const int Kd = DMODEL, Nd = DMODEL;

#pragma unroll
    for (int p = 0; p < 4; ++p) {
        int c = tid + (p << 8);
        int r = c >> 4, c4 = (c & 15) << 2;
        *(float4*)&tile[r][c4] = *(const float4*)(W + (size_t)(k0 + r) * Nd + n0 + c4);
    }
    __syncthreads();
#pragma unroll
    for (int p = 0; p < 4; ++p) {
        int c = tid + (p << 8);
        int n = c >> 4, k4 = (c & 15) << 2;
        if (which < 3) {
            unsigned short* Wt = (which == 0) ? Wqt : (which == 1) ? Wvt : Wot;
            short4v o;
#pragma unroll
            for (int j = 0; j < 4; ++j) o[j] = (short)f2bf(tile[k4 + j][n]);
            *(short4v*)(Wt + (size_t)(n0 + n) * Kd + k0 + k4) = o;
        } else {
            short4v oh, ol;
#pragma unroll
            for (int j = 0; j < 4; ++j) {
                float v = tile[k4 + j][n];
                unsigned short hb = f2bf(v);
                oh[j] = (short)hb;
                ol[j] = (short)f2bf(v - bf2f(hb));
            }
            *(short4v*)(Wkh + (size_t)(n0 + n) * Kd + k0 + k4) = oh;
            *(short4v*)(Wkl + (size_t)(n0 + n) * Kd + k0 + k4) = ol;
        }
    }
}

// ---------------------------------------------------------------------------
__global__ __launch_bounds__(512)
void gemm_bf16_k(const unsigned short* __restrict__ A,
                 const unsigned short* __restrict__ Bt,
                 const float* __restrict__ bias,
                 void* __restrict__ outv, void* __restrict__ outv2,
                 unsigned short* __restrict__ vtout,
                 int M, int N, int K, int mode)
{
    __shared__ __align__(16) unsigned short As[128][72];
    __shared__ __align__(16) unsigned short Bs[128][72];
    const int tid = threadIdx.x;
    const int lane = tid & 63, wave = tid >> 6;
    const int quad = lane >> 4, ln = lane & 15;
    const int mh = (wave >> 2) << 6;
    const int nh = (wave & 3) << 5;
    const int m0 = blockIdx.y * 128, n0 = blockIdx.x * 128;

    f32x4 acc[4][2];
#pragma unroll
    for (int i = 0; i < 4; ++i)
#pragma unroll
        for (int j = 0; j < 2; ++j) acc[i][j] = (f32x4){0.f, 0.f, 0.f, 0.f};

    short8 areg[2], breg[2];
#pragma unroll
    for (int p = 0; p < 2; ++p) {
        int c = tid + (p << 9);
        int row = c >> 3, col8 = (c & 7) << 3;
        areg[p] = *(const short8*)(A + (size_t)(m0 + row) * K + col8);
        breg[p] = *(const short8*)(Bt + (size_t)(n0 + row) * K + col8);
    }

    for (int k0 = 0; k0 < K; k0 += 64) {
        __syncthreads();
#pragma unroll
        for (int p = 0; p < 2; ++p) {
            int c = tid + (p << 9);
            int row = c >> 3, col8 = (c & 7) << 3;
            *(short8*)&As[row][col8] = areg[p];
            *(short8*)&Bs[row][col8] = breg[p];
        }
        __syncthreads();
        if (k0 + 64 < K) {
#pragma unroll
            for (int p = 0; p < 2; ++p) {
                int c = tid + (p << 9);
                int row = c >> 3, col8 = (c & 7) << 3;
                areg[p] = *(const short8*)(A + (size_t)(m0 + row) * K + k0 + 64 + col8);
                breg[p] = *(const short8*)(Bt + (size_t)(n0 + row) * K + k0 + 64 + col8);
            }
        }
#pragma unroll
        for (int ch = 0; ch < 2; ++ch) {
            short8 af[4], bf[2];
#pragma unroll
            for (int mt = 0; mt < 4; ++mt)
                af[mt] = *(const short8*)&As[mh + mt * 16 + ln][ch * 32 + quad * 8];
#pragma unroll
            for (int nt = 0; nt < 2; ++nt)
                bf[nt] = *(const short8*)&Bs[nh + nt * 16 + ln][ch * 32 + quad * 8];
#pragma unroll
            for (int mt = 0; mt < 4; ++mt)
#pragma unroll
                for (int nt = 0; nt < 2; ++nt)
                    acc[mt][nt] = __builtin_amdgcn_mfma_f32_16x16x32_bf16(
                        af[mt], bf[nt], acc[mt][nt], 0, 0, 0);
        }
    }

    if (mode == 0) {
        float* out = (float*)outv;
#pragma unroll
        for (int mt = 0; mt < 4; ++mt)
#pragma unroll
            for (int nt = 0; nt < 2; ++nt)
#pragma unroll
                for (int r = 0; r < 4; ++r) {
                    int m = m0 + mh + mt * 16 + quad * 4 + r;
                    int n = n0 + nh + nt * 16 + ln;
                    out[(size_t)m * N + n] = acc[mt][nt][r] + bias[n];
                }
    } else {
#pragma unroll
        for (int mt = 0; mt < 4; ++mt)
#pragma unroll
            for (int nt = 0; nt < 2; ++nt) {
                int n = n0 + nh + nt * 16 + ln;
                int mb = m0 + mh + mt * 16 + quad * 4;
                int b = mb >> 11, s0 = mb & (SEQ - 1);
                int d = n & 63;
                if (n < DMODEL) {           // Q, pre-scaled (exact)
                    int h = n >> 6;
                    unsigned short* qp_ =
                        (unsigned short*)outv + ((size_t)(b * NH + h) * SEQ + s0) * DHEAD + d;
#pragma unroll
                    for (int r = 0; r < 4; ++r)
                        qp_[(size_t)r * DHEAD] = f2bf(acc[mt][nt][r] * 0.125f);
                } else {                    // V: row-major + transposed
                    int h = (n >> 6) - NH;
                    unsigned short* vp_ =
                        (unsigned short*)outv2 + ((size_t)(b * NH + h) * SEQ + s0) * DHEAD + d;
                    short4v tv;
#pragma unroll
                    for (int r = 0; r < 4; ++r) {
                        unsigned short bv = f2bf(acc[mt][nt][r]);
                        vp_[(size_t)r * DHEAD] = bv;
                        tv[r] = (short)bv;
                    }
                    *(short4v*)(vtout + ((size_t)(b * NH + h) * DHEAD + d) * SEQ + s0) = tv;
                }
            }
    }
}

// ---------------------------------------------------------------------------
__global__ __launch_bounds__(512)
void gemm_kproj_mfma(const unsigned short* __restrict__ xh,
                     const unsigned short* __restrict__ xl,
                     const unsigned short* __restrict__ Wh,
                     const unsigned short* __restrict__ Wl,
                     unsigned short* __restrict__ kout,
                     float* __restrict__ norms2)
{
    __shared__ __align__(16) unsigned short Ah[64][72];
    __shared__ __align__(16) unsigned short Al[64][72];
    __shared__ __align__(16) unsigned short Bh[128][72];
    __shared__ __align__(16) unsigned short Bl[128][72];
    const int K = DMODEL;
    const int tid = threadIdx.x;
    const int lane = tid & 63, wave = tid >> 6;
    const int quad = lane >> 4, ln = lane & 15;
    const int mh = (wave >> 1) << 4;
    const int nh = (wave & 1) << 6;
    const int m0 = blockIdx.y * 64, n0 = blockIdx.x * 128;

    f32x4 acc[4];
#pragma unroll
    for (int j = 0; j < 4; ++j) acc[j] = (f32x4){0.f, 0.f, 0.f, 0.f};

    const int arow = tid >> 3, acol8 = (tid & 7) << 3;
    short8 ahreg, alreg, bhreg[2], blreg[2];
    {
        size_t ga = (size_t)(m0 + arow) * K + acol8;
        ahreg = *(const short8*)(xh + ga);
        alreg = *(const short8*)(xl + ga);
#pragma unroll
        for (int p = 0; p < 2; ++p) {
            int c = tid + (p << 9);
            int row = c >> 3, col8 = (c & 7) << 3;
            size_t gb = (size_t)(n0 + row) * K + col8;
            bhreg[p] = *(const short8*)(Wh + gb);
            blreg[p] = *(const short8*)(Wl + gb);
        }
    }

    for (int k0 = 0; k0 < K; k0 += 64) {
        __syncthreads();
        *(short8*)&Ah[arow][acol8] = ahreg;
        *(short8*)&Al[arow][acol8] = alreg;
#pragma unroll
        for (int p = 0; p < 2; ++p) {
            int c = tid + (p << 9);
            int row = c >> 3, col8 = (c & 7) << 3;
            *(short8*)&Bh[row][col8] = bhreg[p];
            *(short8*)&Bl[row][col8] = blreg[p];
        }
        __syncthreads();
        if (k0 + 64 < K) {
            size_t ga = (size_t)(m0 + arow) * K + k0 + 64 + acol8;
            ahreg = *(const short8*)(xh + ga);
            alreg = *(const short8*)(xl + ga);
#pragma unroll
            for (int p = 0; p < 2; ++p) {
                int c = tid + (p << 9);
                int row = c >> 3, col8 = (c & 7) << 3;
                size_t gb = (size_t)(n0 + row) * K + k0 + 64 + col8;
                bhreg[p] = *(const short8*)(Wh + gb);
                blreg[p] = *(const short8*)(Wl + gb);
            }
        }
#pragma unroll
        for (int ch = 0; ch < 2; ++ch) {
            short8 bh4[4], bl4[4];
#pragma unroll
            for (int nt = 0; nt < 4; ++nt) {
                bh4[nt] = *(const short8*)&Bh[nh + nt * 16 + ln][ch * 32 + quad * 8];
                bl4[nt] = *(const short8*)&Bl[nh + nt * 16 + ln][ch * 32 + quad * 8];
            }
            short8 ah = *(const short8*)&Ah[mh + ln][ch * 32 + quad * 8];
            short8 al = *(const short8*)&Al[mh + ln][ch * 32 + quad * 8];
#pragma unroll
            for (int nt = 0; nt < 4; ++nt) {
                acc[nt] = __builtin_amdgcn_mfma_f32_16x16x32_bf16(ah, bh4[nt], acc[nt], 0, 0, 0);
                acc[nt] = __builtin_amdgcn_mfma_f32_16x16x32_bf16(ah, bl4[nt], acc[nt], 0, 0, 0);
                acc[nt] = __builtin_amdgcn_mfma_f32_16x16x32_bf16(al, bh4[nt], acc[nt], 0, 0, 0);
            }
        }
    }

    const int h = (n0 + nh) >> 6;
#pragma unroll
    for (int r = 0; r < 4; ++r) {
        int m = m0 + mh + quad * 4 + r;
        int b = m >> 11, s = m & (SEQ - 1);
        size_t rowbase = ((size_t)(b * NH + h) * SEQ + s) * DHEAD;
#pragma unroll
        for (int nt = 0; nt < 4; ++nt)
            kout[rowbase + nt * 16 + ln] = f2bf(acc[nt][r]);
        float s2 = acc[0][r] * acc[0][r] + acc[1][r] * acc[1][r] +
                   acc[2][r] * acc[2][r] + acc[3][r] * acc[3][r];
#pragma unroll
        for (int off = 1; off <= 8; off <<= 1)
            s2 += __shfl_xor(s2, off);
        if (ln == 0)
            norms2[(size_t)(b * NH + h) * SEQ + s] = s2;
    }
}

// ---------------------------------------------------------------------------
__global__ __launch_bounds__(512)
void topk_gather_k(const float* __restrict__ norms2,
                   const unsigned short* __restrict__ k,
                   const unsigned short* __restrict__ v,
                   unsigned short* __restrict__ gk,
                   unsigned short* __restrict__ gvt)
{
    __shared__ unsigned long long keys[SEQ];
    __shared__ int tix[NGPAD];
    __shared__ __align__(16) unsigned short T[64][72];
    const int bh = blockIdx.x;
    const int tid = threadIdx.x;
    const float* nb = norms2 + (size_t)bh * SEQ;
    const size_t base = (size_t)bh * SEQ * DHEAD;

    for (int i = tid; i < SEQ; i += 512) {
        float nrm = sqrtf(nb[i]);
        keys[i] = ((unsigned long long)__float_as_uint(nrm) << 32) |
                  (unsigned int)(0xFFFFFFFFu - (unsigned int)i);
    }
    __syncthreads();
    for (int kk = 2; kk <= SEQ; kk <<= 1) {
        for (int j = kk >> 1; j > 0; j >>= 1) {
            for (int i = tid; i < SEQ; i += 512) {
                int ixj = i ^ j;
                if (ixj > i) {
                    unsigned long long a = keys[i], b = keys[ixj];
                    bool up = ((i & kk) == 0);
                    if ((a > b) == up) { keys[i] = b; keys[ixj] = a; }
                }
            }
            __syncthreads();
        }
    }
    if (tid < NGPAD) {
        tix[tid] = (tid < NG)
            ? (int)(0xFFFFFFFFu - (unsigned int)(keys[SEQ - 1 - tid] & 0xFFFFFFFFu))
            : 0;
    }
    __syncthreads();

    for (int t = 0; t < NGPAD / 64; ++t) {
        {
            int idx = tid;
            int row = idx >> 3, col8 = (idx & 7) << 3;
            int g = t * 64 + row;
            short8 kv = (short8)0, vv = (short8)0;
            if (g < NG) {
                int sidx = tix[g];
                kv = *(const short8*)(k + base + (size_t)sidx * DHEAD + col8);
                vv = *(const short8*)(v + base + (size_t)sidx * DHEAD + col8);
            }
            *(short8*)(gk + ((size_t)bh * NGPAD + g) * DHEAD + col8) = kv;
            *(short8*)&T[row][col8] = vv;
        }
        __syncthreads();
        {
            int idx = tid;
            int d = idx >> 3, k8 = (idx & 7) << 3;
            short8 o;
#pragma unroll
            for (int i = 0; i < 8; ++i) o[i] = (short)T[k8 + i][d];
            *(short8*)(gvt + ((size_t)bh * DHEAD + d) * NGPAD + t * 64 + k8) = o;
        }
        __syncthreads();
    }
}

// ---------------------------------------------------------------------------
// Fused attention, key-parity wave groups.
// 512 thr = 8 waves: grp = wave>>2 (0: even tiles, 1: odd), wg = wave&3.
// Wave owns q-rows wg*32 + g*16 (+quad*4+r), g in {0,1}; waves w and w+4 own
// the SAME rows over disjoint key tiles; partials add (no online max).
// Per iteration both groups compute on their own KV buffer pair.
// ---------------------------------------------------------------------------
__global__ __launch_bounds__(512, 4)
void attn_fused_k(const unsigned short* __restrict__ qb,
                  const unsigned short* __restrict__ kb,
                  const unsigned short* __restrict__ vt,
                  const unsigned short* __restrict__ gk,
                  const unsigned short* __restrict__ gvt,
                  const unsigned short* __restrict__ Wgt,
                  const float* __restrict__ gamma,
                  const float* __restrict__ beta,
                  const float* __restrict__ bg,
                  unsigned short* __restrict__ fused)
{
    __shared__ __align__(16) unsigned short Ks[2][64][72];
    __shared__ __align__(16) unsigned short Vt[2][64][72];
    __shared__ __align__(16) unsigned short Ps[256][40];   // 32-key halves
    unsigned short (*Wgs)[136] = (unsigned short (*)[136])&Ks[0][0][0]; // 8704 <= 9216
    float* scrO = (float*)&Ps[0][0];      // 5120 floats
    float* scr3 = (float*)&Vt[0][0][0];   // 4608 floats

    const int flat = blockIdx.x;
    const int bh = ((flat >> 7) << 3) | (flat & 7);   // flat%8 == bh%8 (XCD)
    const int q0 = ((flat >> 3) & 15) * 128;
    const int tid = threadIdx.x;
    const int lane = tid & 63, wave = tid >> 6;
    const int grp = wave >> 2, wg = wave & 3;
    const int quad = lane >> 4, ln = lane & 15;
    const size_t base = (size_t)bh * SEQ * DHEAD;
    const unsigned short* gkb = gk + (size_t)bh * NGPAD * DHEAD;
    const unsigned short* gvb = gvt + (size_t)bh * DHEAD * NGPAD;
    const int tid256 = tid & 255;

    short8 qf[2][2];
#pragma unroll
    for (int g = 0; g < 2; ++g) {
        const unsigned short* qp =
            qb + base + (size_t)(q0 + wg * 32 + g * 16 + ln) * DHEAD;
        qf[g][0] = *(const short8*)(qp + quad * 8);
        qf[g][1] = *(const short8*)(qp + 32 + quad * 8);
    }

    f32x4 O[2][4], Og[2][4];
#pragma unroll
    for (int g = 0; g < 2; ++g)
#pragma unroll
        for (int nt = 0; nt < 4; ++nt) {
            O[g][nt] = (f32x4){0.f, 0.f, 0.f, 0.f};
            Og[g][nt] = (f32x4){0.f, 0.f, 0.f, 0.f};
        }
    float ls[2][4] = {{0.f, 0.f, 0.f, 0.f}, {0.f, 0.f, 0.f, 0.f}};
    float lg[2][4] = {{0.f, 0.f, 0.f, 0.f}, {0.f, 0.f, 0.f, 0.f}};

    // staging: group G's 256 threads stage buffer G (its own tiles)
    short8 kreg[2], vreg[2];
#pragma unroll
    for (int p = 0; p < 2; ++p) {
        int idx = tid256 * 2 + p;
        int row = idx >> 3, col8 = (idx & 7) << 3;
        kreg[p] = *(const short8*)(kb + base + (size_t)(grp * 64 + row) * DHEAD + col8);
        vreg[p] = *(const short8*)(vt + base + (size_t)row * SEQ + grp * 64 + col8);
    }

    for (int it = 0; it < 18; ++it) {
        const int mytile = 2 * it + grp;
        const bool isglob = (mytile >= 32);
        const int tg64 = (mytile - 32) * 64;
        __syncthreads();
#pragma unroll
        for (int p = 0; p < 2; ++p) {
            int idx = tid256 * 2 + p;
            int row = idx >> 3, col8 = (idx & 7) << 3;
            *(short8*)&Ks[grp][row][col8] = kreg[p];
            *(short8*)&Vt[grp][row][col8] = vreg[p];
        }
        __syncthreads();
        {   // prefetch tile+2
            int nxt = mytile + 2;
            if (nxt < 32) {
#pragma unroll
                for (int p = 0; p < 2; ++p) {
                    int idx = tid256 * 2 + p;
                    int row = idx >> 3, col8 = (idx & 7) << 3;
                    kreg[p] = *(const short8*)(kb + base + (size_t)(nxt * 64 + row) * DHEAD + col8);
                    vreg[p] = *(const short8*)(vt + base + (size_t)row * SEQ + nxt * 64 + col8);
                }
            } else if (nxt < 36) {
                int tg = nxt - 32;
#pragma unroll
                for (int p = 0; p < 2; ++p) {
                    int idx = tid256 * 2 + p;
                    int row = idx >> 3, col8 = (idx & 7) << 3;
                    kreg[p] = *(const short8*)(gkb + (size_t)(tg * 64 + row) * DHEAD + col8);
                    vreg[p] = *(const short8*)(gvb + (size_t)row * NGPAD + tg * 64 + col8);
                }
            }
        }

#pragma unroll
        for (int ch = 0; ch < 2; ++ch) {
            short8 kf0[2], kf1[2];
#pragma unroll
            for (int j = 0; j < 2; ++j) {
                int ntj = ch * 2 + j;
                kf0[j] = *(const short8*)&Ks[grp][ntj * 16 + ln][quad * 8];
                kf1[j] = *(const short8*)&Ks[grp][ntj * 16 + ln][32 + quad * 8];
            }
#pragma unroll
            for (int g = 0; g < 2; ++g) {
                f32x4 s[2];
#pragma unroll
                for (int j = 0; j < 2; ++j) {
                    s[j] = (f32x4){0.f, 0.f, 0.f, 0.f};
                    s[j] = __builtin_amdgcn_mfma_f32_16x16x32_bf16(qf[g][0], kf0[j], s[j], 0, 0, 0);
                    s[j] = __builtin_amdgcn_mfma_f32_16x16x32_bf16(qf[g][1], kf1[j], s[j], 0, 0, 0);
                }
                if (!isglob) {
#pragma unroll
                    for (int j = 0; j < 2; ++j)
#pragma unroll
                        for (int r = 0; r < 4; ++r) {
                            float p = __expf(s[j][r]);
                            unsigned int us = __float_as_uint(p) >> 16;   // trunc bf16
                            Ps[wave * 32 + g * 16 + quad * 4 + r][j * 16 + ln] = (unsigned short)us;
                            ls[g][r] += __uint_as_float(us << 16);        // matched
                        }
                } else {
#pragma unroll
                    for (int j = 0; j < 2; ++j) {
                        bool valid = (tg64 + (ch * 2 + j) * 16 + ln) < NG;
#pragma unroll
                        for (int r = 0; r < 4; ++r) {
                            float p = valid ? __expf(s[j][r]) : 0.f;
                            unsigned int us = __float_as_uint(p) >> 16;
                            Ps[wave * 32 + g * 16 + quad * 4 + r][j * 16 + ln] = (unsigned short)us;
                            lg[g][r] += __uint_as_float(us << 16);
                        }
                    }
                }
            }
            short8 vf[4];
#pragma unroll
            for (int ntp = 0; ntp < 4; ++ntp)
                vf[ntp] = *(const short8*)&Vt[grp][ntp * 16 + ln][ch * 32 + quad * 8];
#pragma unroll
            for (int g = 0; g < 2; ++g) {
                short8 pf = *(const short8*)&Ps[wave * 32 + g * 16 + ln][quad * 8];
                if (!isglob) {
#pragma unroll
                    for (int ntp = 0; ntp < 4; ++ntp)
                        O[g][ntp] = __builtin_amdgcn_mfma_f32_16x16x32_bf16(pf, vf[ntp], O[g][ntp], 0, 0, 0);
                } else {
#pragma unroll
                    for (int ntp = 0; ntp < 4; ++ntp)
                        Og[g][ntp] = __builtin_amdgcn_mfma_f32_16x16x32_bf16(pf, vf[ntp], Og[g][ntp], 0, 0, 0);
                }
            }
        }
    }

    // ---- epilogue: exchange partials between wave pairs (w <-> w+4) ----
    __syncthreads();
    // stage Wgs over Ks (dead), write scr3 (other-g l partials), phase 1a
#pragma unroll
    for (int p = 0; p < 2; ++p) {
        int idx8 = tid * 2 + p;
        int dg = idx8 >> 4, c8 = (idx8 & 15) << 3;
        *(short8*)&Wgs[dg][c8] = *(const short8*)(Wgt + idx8 * 8);
    }
#pragma unroll
    for (int off = 1; off <= 8; off <<= 1)
#pragma unroll
        for (int g = 0; g < 2; ++g)
#pragma unroll
            for (int r = 0; r < 4; ++r) {
                ls[g][r] += __shfl_xor(ls[g][r], off);
                lg[g][r] += __shfl_xor(lg[g][r], off);
            }
    {
        int og = grp ^ 1;
#pragma unroll
        for (int r = 0; r < 4; ++r) {
            scr3[((size_t)wave * 64 + lane) * 8 + r] = ls[og][r];
            scr3[((size_t)wave * 64 + lane) * 8 + 4 + r] = lg[og][r];
        }
    }
    const int slot = wg * 1024 + lane * 16;
    if (grp == 0)
#pragma unroll
        for (int nt = 0; nt < 4; ++nt)
#pragma unroll
            for (int r = 0; r < 4; ++r) scrO[slot + nt * 4 + r] = O[1][nt][r];
    __syncthreads();
    if (grp == 1) {
#pragma unroll
        for (int nt = 0; nt < 4; ++nt)
#pragma unroll
            for (int r = 0; r < 4; ++r) O[1][nt][r] += scrO[slot + nt * 4 + r];
#pragma unroll
        for (int nt = 0; nt < 4; ++nt)
#pragma unroll
            for (int r = 0; r < 4; ++r) scrO[slot + nt * 4 + r] = O[0][nt][r];
    }
    __syncthreads();
    if (grp == 0) {
#pragma unroll
        for (int nt = 0; nt < 4; ++nt)
#pragma unroll
            for (int r = 0; r < 4; ++r) O[0][nt][r] += scrO[slot + nt * 4 + r];
#pragma unroll
        for (int nt = 0; nt < 4; ++nt)
#pragma unroll
            for (int r = 0; r < 4; ++r) scrO[slot + nt * 4 + r] = Og[1][nt][r];
    }
    __syncthreads();
    if (grp == 1) {
#pragma unroll
        for (int nt = 0; nt < 4; ++nt)
#pragma unroll
            for (int r = 0; r < 4; ++r) Og[1][nt][r] += scrO[slot + nt * 4 + r];
#pragma unroll
        for (int nt = 0; nt < 4; ++nt)
#pragma unroll
            for (int r = 0; r < 4; ++r) scrO[slot + nt * 4 + r] = Og[0][nt][r];
    }
    __syncthreads();
    if (grp == 0)
#pragma unroll
        for (int nt = 0; nt < 4; ++nt)
#pragma unroll
            for (int r = 0; r < 4; ++r) Og[0][nt][r] += scrO[slot + nt * 4 + r];
    float lsum[4], lgsum[4];
    {
        int prt = wave ^ 4;
#pragma unroll
        for (int r = 0; r < 4; ++r) {
            lsum[r] = ls[grp][r] + scr3[((size_t)prt * 64 + lane) * 8 + r];
            lgsum[r] = lg[grp][r] + scr3[((size_t)prt * 64 + lane) * 8 + 4 + r];
        }
    }
    __syncthreads();   // scrO reads done before gate staging reuses Ps

    // ---- per-wave epilogue: 16 rows (g = grp) ----
    const int myg = grp;
    float xs[4][4];
#pragma unroll
    for (int r = 0; r < 4; ++r) {
        float inv = 1.f / lgsum[r];
#pragma unroll
        for (int nt = 0; nt < 4; ++nt) xs[nt][r] = Og[myg][nt][r] * inv;
    }
    float mu[4], rsd[4];
#pragma unroll
    for (int r = 0; r < 4; ++r) {
        float sm = xs[0][r] + xs[1][r] + xs[2][r] + xs[3][r];
#pragma unroll
        for (int off = 1; off <= 8; off <<= 1) sm += __shfl_xor(sm, off);
        mu[r] = sm * (1.f / 64.f);
    }
#pragma unroll
    for (int r = 0; r < 4; ++r) {
        float sv = 0.f;
#pragma unroll
        for (int nt = 0; nt < 4; ++nt) {
            float d = xs[nt][r] - mu[r];
            sv += d * d;
        }
#pragma unroll
        for (int off = 1; off <= 8; off <<= 1) sv += __shfl_xor(sv, off);
        rsd[r] = rsqrtf(sv * (1.f / 64.f) + LNEPS);
    }
#pragma unroll
    for (int nt = 0; nt < 4; ++nt) {
        float gmv = gamma[nt * 16 + ln], bb = beta[nt * 16 + ln];
#pragma unroll
        for (int r = 0; r < 4; ++r)
            xs[nt][r] = (xs[nt][r] - mu[r]) * rsd[r] * gmv + bb;
    }
    float lf[4][4];
#pragma unroll
    for (int nt = 0; nt < 4; ++nt)
#pragma unroll
        for (int r = 0; r < 4; ++r) lf[nt][r] = O[myg][nt][r] / lsum[r];

    f32x4 gacc[4];
#pragma unroll
    for (int ng = 0; ng < 4; ++ng) {
        float bgv = bg[ng * 16 + ln];
        gacc[ng] = (f32x4){bgv, bgv, bgv, bgv};
    }
    // gate pass 1: local half (cat dims 0..63), staged per 32-dim chunk
#pragma unroll
    for (int ch = 0; ch < 2; ++ch) {
#pragma unroll
        for (int j = 0; j < 2; ++j) {
            int nt = ch * 2 + j;
#pragma unroll
            for (int r = 0; r < 4; ++r)
                Ps[wave * 32 + quad * 4 + r][j * 16 + ln] = f2bf(lf[nt][r]);
        }
        short8 af = *(const short8*)&Ps[wave * 32 + ln][quad * 8];
#pragma unroll
        for (int ng = 0; ng < 4; ++ng) {
            short8 bf = *(const short8*)&Wgs[ng * 16 + ln][ch * 32 + quad * 8];
            gacc[ng] = __builtin_amdgcn_mfma_f32_16x16x32_bf16(af, bf, gacc[ng], 0, 0, 0);
        }
    }
    // gate pass 2: global half (cat dims 64..127)
#pragma unroll
    for (int ch = 0; ch < 2; ++ch) {
#pragma unroll
        for (int j = 0; j < 2; ++j) {
            int nt = ch * 2 + j;
#pragma unroll
            for (int r = 0; r < 4; ++r)
                Ps[wave * 32 + quad * 4 + r][j * 16 + ln] = f2bf(xs[nt][r]);
        }
        short8 af = *(const short8*)&Ps[wave * 32 + ln][quad * 8];
#pragma unroll
        for (int ng = 0; ng < 4; ++ng) {
            short8 bf = *(const short8*)&Wgs[ng * 16 + ln][64 + ch * 32 + quad * 8];
            gacc[ng] = __builtin_amdgcn_mfma_f32_16x16x32_bf16(af, bf, gacc[ng], 0, 0, 0);
        }
    }

    const int b = bh >> 4, h = bh & 15;
#pragma unroll
    for (int ng = 0; ng < 4; ++ng)
#pragma unroll
        for (int r = 0; r < 4; ++r) {
            float gt = 1.f / (1.f + __expf(-gacc[ng][r]));
            float f = gt * lf[ng][r] + (1.f - gt) * xs[ng][r];
            int s = q0 + wg * 32 + myg * 16 + quad * 4 + r;
            fused[((size_t)(b * SEQ + s)) * DMODEL + h * DHEAD + ng * 16 + ln] = f2bf(f);
        }
}

// ---------------------------------------------------------------------------
extern "C" void kernel_launch(void* const* d_in, const int* in_sizes, int n_in,
                              void* d_out, int out_size, void* d_ws, size_t ws_size,
                              hipStream_t stream)
{
    (void)in_sizes; (void)n_in; (void)out_size; (void)ws_size;
    const float* x    = (const float*)d_in[0];
    const float* Wq   = (const float*)d_in[1];
    const float* Wk   = (const float*)d_in[2];
    const float* Wv   = (const float*)d_in[3];
    const float* Wo   = (const float*)d_in[4];
    const float* bo   = (const float*)d_in[5];
    const float* ln_g = (const float*)d_in[6];
    const float* ln_b = (const float*)d_in[7];
    const float* Wg   = (const float*)d_in[8];
    const float* bg   = (const float*)d_in[9];

    char* w = (char*)d_ws;
    const size_t MB = 1024ull * 1024ull;
    unsigned short* kb16  = (unsigned short*)(w);
    unsigned short* qb16  = (unsigned short*)(w + 8 * MB);
    unsigned short* vb16  = (unsigned short*)(w + 16 * MB);
    unsigned short* vt16  = (unsigned short*)(w + 24 * MB);
    unsigned short* xh    = (unsigned short*)(w + 32 * MB);
    unsigned short* xl    = (unsigned short*)(w + 40 * MB);
    unsigned short* Wqt   = (unsigned short*)(w + 48 * MB);
    unsigned short* Wvt   = (unsigned short*)(w + 50 * MB);   // contiguous after Wqt
    unsigned short* Wot   = (unsigned short*)(w + 52 * MB);
    unsigned short* Wkh   = (unsigned short*)(w + 54 * MB);
    unsigned short* Wkl   = (unsigned short*)(w + 56 * MB);
    unsigned short* Wgt   = (unsigned short*)(w + 58 * MB);
    float*          norms2= (float*)(w + 59 * MB);
    unsigned short* gk16  = (unsigned short*)(w + 60 * MB);
    unsigned short* gvt16 = (unsigned short*)(w + 61 * MB);
    unsigned short* fusedb = xh;   // xh dead after projections

    const int M = 4096, N = 1024, K = 1024;

    prep_k<<<3073, 256, 0, stream>>>(x, Wq, Wv, Wo, Wk, Wg,
                                     xh, xl, Wqt, Wvt, Wot, Wkh, Wkl, Wgt);

    dim3 gqv(2048 / 128, M / 128);
    gemm_bf16_k<<<gqv, 512, 0, stream>>>(xh, Wqt, nullptr, qb16, vb16, vt16,
                                         M, 2048, K, 3);

    dim3 gkp(N / 128, M / 64);
    gemm_kproj_mfma<<<gkp, 512, 0, stream>>>(xh, xl, Wkh, Wkl, kb16, norms2);

    topk_gather_k<<<BHT, 512, 0, stream>>>(norms2, kb16, vb16, gk16, gvt16);

    attn_fused_k<<<512, 512, 0, stream>>>(qb16, kb16, vt16, gk16, gvt16, Wgt,
                                          ln_g, ln_b, bg, fusedb);

    dim3 go_(N / 128, M / 128);
    gemm_bf16_k<<<go_, 512, 0, stream>>>(fusedb, Wot, bo, (float*)d_out, nullptr,
                                         nullptr, M, N, K, 0);
}

// Round 9
// 295.581 us; speedup vs baseline: 1.7508x; 1.7508x over previous
//
#include <hip/hip_runtime.h>

// SegmentedAttention round 9 = r6 attn (measured 91us) + r7 non-attn
// (measured ~186us). r8's key-split registers spilled (launch_bounds cap
// 128 VGPR vs ~160 needed -> 1.27GB scratch traffic); reverted.
// ws (MB): kb16@0(8) qb16@8(8) vb16@16(8) vt16@24(8) xh@32(8,=fusedb)
//   xl@40(8) Wqt@48(2) Wvt@50(2) Wot@52(2) Wkh@54(2) Wkl@56(2) Wgt@58(1)
//   norms2@59(1) gk@60(1) gvt@61(1) -> 62MB

constexpr int SEQ    = 2048;
constexpr int DMODEL = 1024;
constexpr int NH     = 16;
constexpr int DHEAD  = 64;
constexpr int BHT    = 32;
constexpr int NG     = 204;
constexpr int NGPAD  = 256;
constexpr float LNEPS = 1e-5f;

typedef __attribute__((ext_vector_type(8))) short short8;
typedef __attribute__((ext_vector_type(4))) short short4v;
typedef __attribute__((ext_vector_type(4))) float f32x4;

__device__ __forceinline__ unsigned short f2bf(float f) {
    unsigned int u = __float_as_uint(f);
    u += 0x7FFFu + ((u >> 16) & 1u);
    return (unsigned short)(u >> 16);
}
__device__ __forceinline__ float bf2f(unsigned short b) {
    return __uint_as_float(((unsigned int)b) << 16);
}

// ---------------------------------------------------------------------------
// prep: blocks [0,2048): x hilo split; [2048,3072): weight transposes;
// block 3072: Wg^T bf16.
// ---------------------------------------------------------------------------
__global__ __launch_bounds__(256)
void prep_k(const float* __restrict__ x,
            const float* __restrict__ Wq, const float* __restrict__ Wv,
            const float* __restrict__ Wo, const float* __restrict__ Wk,
            const float* __restrict__ Wg,
            unsigned short* __restrict__ xh, unsigned short* __restrict__ xl,
            unsigned short* __restrict__ Wqt, unsigned short* __restrict__ Wvt,
            unsigned short* __restrict__ Wot, unsigned short* __restrict__ Wkh,
            unsigned short* __restrict__ Wkl, unsigned short* __restrict__ Wgt)
{
    const int bid = blockIdx.x;
    const int tid = threadIdx.x;

    if (bid < 2048) {
        int i = (bid * 256 + tid) << 3;
        short8 h, l;
#pragma unroll
        for (int j = 0; j < 8; ++j) {
            float v = x[i + j];
            unsigned short hb = f2bf(v);
            h[j] = (short)hb;
            l[j] = (short)f2bf(v - bf2f(hb));
        }
        *(short8*)(xh + i) = h;
        *(short8*)(xl + i) = l;
        return;
    }
    if (bid == 3072) {
#pragma unroll
        for (int i = 0; i < 32; ++i) {
            int o = tid * 32 + i;
            int dg = o >> 7, jj = o & 127;
            Wgt[o] = f2bf(Wg[jj * 64 + dg]);
        }
        return;
    }

    __shared__ float tile[64][68];
    const int sub = bid - 2048;
    const int which = sub >> 8;             // 0:Wq 1:Wv 2:Wo 3:Wk
    const int b = sub & 255;
    const int n0 = (b & 15) * 64, k0 = (b >> 4) * 64;
    const float* W = (which == 0) ? Wq : (which == 1) ? Wv : (which == 2) ? Wo : Wk;
    const int Kd = DMODEL, Nd = DMODEL;

#pragma unroll
    for (int p = 0; p < 4; ++p) {
        int c = tid + (p << 8);
        int r = c >> 4, c4 = (c & 15) << 2;
        *(float4*)&tile[r][c4] = *(const float4*)(W + (size_t)(k0 + r) * Nd + n0 + c4);
    }
    __syncthreads();
#pragma unroll
    for (int p = 0; p < 4; ++p) {
        int c = tid + (p << 8);
        int n = c >> 4, k4 = (c & 15) << 2;
        if (which < 3) {
            unsigned short* Wt = (which == 0) ? Wqt : (which == 1) ? Wvt : Wot;
            short4v o;
#pragma unroll
            for (int j = 0; j < 4; ++j) o[j] = (short)f2bf(tile[k4 + j][n]);
            *(short4v*)(Wt + (size_t)(n0 + n) * Kd + k0 + k4) = o;
        } else {
            short4v oh, ol;
#pragma unroll
            for (int j = 0; j < 4; ++j) {
                float v = tile[k4 + j][n];
                unsigned short hb = f2bf(v);
                oh[j] = (short)hb;
                ol[j] = (short)f2bf(v - bf2f(hb));
            }
            *(short4v*)(Wkh + (size_t)(n0 + n) * Kd + k0 + k4) = oh;
            *(short4v*)(Wkl + (size_t)(n0 + n) * Kd + k0 + k4) = ol;
        }
    }
}

// ---------------------------------------------------------------------------
// bf16 MFMA GEMM, 512 thr, 128x128 tile, 8 waves 2x4, reg-prefetch dbuf.
// mode 0: fp32 out = acc + bias.
// mode 3: Q|V: n<1024 -> qb (acc*0.125); n>=1024 -> vb AND vt (transposed).
// ---------------------------------------------------------------------------
__global__ __launch_bounds__(512)
void gemm_bf16_k(const unsigned short* __restrict__ A,
                 const unsigned short* __restrict__ Bt,
                 const float* __restrict__ bias,
                 void* __restrict__ outv, void* __restrict__ outv2,
                 unsigned short* __restrict__ vtout,
                 int M, int N, int K, int mode)
{
    __shared__ __align__(16) unsigned short As[128][72];
    __shared__ __align__(16) unsigned short Bs[128][72];
    const int tid = threadIdx.x;
    const int lane = tid & 63, wave = tid >> 6;
    const int quad = lane >> 4, ln = lane & 15;
    const int mh = (wave >> 2) << 6;
    const int nh = (wave & 3) << 5;
    const int m0 = blockIdx.y * 128, n0 = blockIdx.x * 128;

    f32x4 acc[4][2];
#pragma unroll
    for (int i = 0; i < 4; ++i)
#pragma unroll
        for (int j = 0; j < 2; ++j) acc[i][j] = (f32x4){0.f, 0.f, 0.f, 0.f};

    short8 areg[2], breg[2];
#pragma unroll
    for (int p = 0; p < 2; ++p) {
        int c = tid + (p << 9);
        int row = c >> 3, col8 = (c & 7) << 3;
        areg[p] = *(const short8*)(A + (size_t)(m0 + row) * K + col8);
        breg[p] = *(const short8*)(Bt + (size_t)(n0 + row) * K + col8);
    }

    for (int k0 = 0; k0 < K; k0 += 64) {
        __syncthreads();
#pragma unroll
        for (int p = 0; p < 2; ++p) {
            int c = tid + (p << 9);
            int row = c >> 3, col8 = (c & 7) << 3;
            *(short8*)&As[row][col8] = areg[p];
            *(short8*)&Bs[row][col8] = breg[p];
        }
        __syncthreads();
        if (k0 + 64 < K) {
#pragma unroll
            for (int p = 0; p < 2; ++p) {
                int c = tid + (p << 9);
                int row = c >> 3, col8 = (c & 7) << 3;
                areg[p] = *(const short8*)(A + (size_t)(m0 + row) * K + k0 + 64 + col8);
                breg[p] = *(const short8*)(Bt + (size_t)(n0 + row) * K + k0 + 64 + col8);
            }
        }
#pragma unroll
        for (int ch = 0; ch < 2; ++ch) {
            short8 af[4], bf[2];
#pragma unroll
            for (int mt = 0; mt < 4; ++mt)
                af[mt] = *(const short8*)&As[mh + mt * 16 + ln][ch * 32 + quad * 8];
#pragma unroll
            for (int nt = 0; nt < 2; ++nt)
                bf[nt] = *(const short8*)&Bs[nh + nt * 16 + ln][ch * 32 + quad * 8];
#pragma unroll
            for (int mt = 0; mt < 4; ++mt)
#pragma unroll
                for (int nt = 0; nt < 2; ++nt)
                    acc[mt][nt] = __builtin_amdgcn_mfma_f32_16x16x32_bf16(
                        af[mt], bf[nt], acc[mt][nt], 0, 0, 0);
        }
    }

    if (mode == 0) {
        float* out = (float*)outv;
#pragma unroll
        for (int mt = 0; mt < 4; ++mt)
#pragma unroll
            for (int nt = 0; nt < 2; ++nt)
#pragma unroll
                for (int r = 0; r < 4; ++r) {
                    int m = m0 + mh + mt * 16 + quad * 4 + r;
                    int n = n0 + nh + nt * 16 + ln;
                    out[(size_t)m * N + n] = acc[mt][nt][r] + bias[n];
                }
    } else {
#pragma unroll
        for (int mt = 0; mt < 4; ++mt)
#pragma unroll
            for (int nt = 0; nt < 2; ++nt) {
                int n = n0 + nh + nt * 16 + ln;
                int mb = m0 + mh + mt * 16 + quad * 4;
                int b = mb >> 11, s0 = mb & (SEQ - 1);
                int d = n & 63;
                if (n < DMODEL) {           // Q, pre-scaled (exact)
                    int h = n >> 6;
                    unsigned short* qp_ =
                        (unsigned short*)outv + ((size_t)(b * NH + h) * SEQ + s0) * DHEAD + d;
#pragma unroll
                    for (int r = 0; r < 4; ++r)
                        qp_[(size_t)r * DHEAD] = f2bf(acc[mt][nt][r] * 0.125f);
                } else {                    // V: row-major + transposed
                    int h = (n >> 6) - NH;
                    unsigned short* vp_ =
                        (unsigned short*)outv2 + ((size_t)(b * NH + h) * SEQ + s0) * DHEAD + d;
                    short4v tv;
#pragma unroll
                    for (int r = 0; r < 4; ++r) {
                        unsigned short bv = f2bf(acc[mt][nt][r]);
                        vp_[(size_t)r * DHEAD] = bv;
                        tv[r] = (short)bv;
                    }
                    *(short4v*)(vtout + ((size_t)(b * NH + h) * DHEAD + d) * SEQ + s0) = tv;
                }
            }
    }
}

// ---------------------------------------------------------------------------
// Compensated K projection: 512 thr, 64x128 tile, reg-prefetch dbuf.
// ---------------------------------------------------------------------------
__global__ __launch_bounds__(512)
void gemm_kproj_mfma(const unsigned short* __restrict__ xh,
                     const unsigned short* __restrict__ xl,
                     const unsigned short* __restrict__ Wh,
                     const unsigned short* __restrict__ Wl,
                     unsigned short* __restrict__ kout,
                     float* __restrict__ norms2)
{
    __shared__ __align__(16) unsigned short Ah[64][72];
    __shared__ __align__(16) unsigned short Al[64][72];
    __shared__ __align__(16) unsigned short Bh[128][72];
    __shared__ __align__(16) unsigned short Bl[128][72];
    const int K = DMODEL;
    const int tid = threadIdx.x;
    const int lane = tid & 63, wave = tid >> 6;
    const int quad = lane >> 4, ln = lane & 15;
    const int mh = (wave >> 1) << 4;
    const int nh = (wave & 1) << 6;
    const int m0 = blockIdx.y * 64, n0 = blockIdx.x * 128;

    f32x4 acc[4];
#pragma unroll
    for (int j = 0; j < 4; ++j) acc[j] = (f32x4){0.f, 0.f, 0.f, 0.f};

    const int arow = tid >> 3, acol8 = (tid & 7) << 3;
    short8 ahreg, alreg, bhreg[2], blreg[2];
    {
        size_t ga = (size_t)(m0 + arow) * K + acol8;
        ahreg = *(const short8*)(xh + ga);
        alreg = *(const short8*)(xl + ga);
#pragma unroll
        for (int p = 0; p < 2; ++p) {
            int c = tid + (p << 9);
            int row = c >> 3, col8 = (c & 7) << 3;
            size_t gb = (size_t)(n0 + row) * K + col8;
            bhreg[p] = *(const short8*)(Wh + gb);
            blreg[p] = *(const short8*)(Wl + gb);
        }
    }

    for (int k0 = 0; k0 < K; k0 += 64) {
        __syncthreads();
        *(short8*)&Ah[arow][acol8] = ahreg;
        *(short8*)&Al[arow][acol8] = alreg;
#pragma unroll
        for (int p = 0; p < 2; ++p) {
            int c = tid + (p << 9);
            int row = c >> 3, col8 = (c & 7) << 3;
            *(short8*)&Bh[row][col8] = bhreg[p];
            *(short8*)&Bl[row][col8] = blreg[p];
        }
        __syncthreads();
        if (k0 + 64 < K) {
            size_t ga = (size_t)(m0 + arow) * K + k0 + 64 + acol8;
            ahreg = *(const short8*)(xh + ga);
            alreg = *(const short8*)(xl + ga);
#pragma unroll
            for (int p = 0; p < 2; ++p) {
                int c = tid + (p << 9);
                int row = c >> 3, col8 = (c & 7) << 3;
                size_t gb = (size_t)(n0 + row) * K + k0 + 64 + col8;
                bhreg[p] = *(const short8*)(Wh + gb);
                blreg[p] = *(const short8*)(Wl + gb);
            }
        }
#pragma unroll
        for (int ch = 0; ch < 2; ++ch) {
            short8 bh4[4], bl4[4];
#pragma unroll
            for (int nt = 0; nt < 4; ++nt) {
                bh4[nt] = *(const short8*)&Bh[nh + nt * 16 + ln][ch * 32 + quad * 8];
                bl4[nt] = *(const short8*)&Bl[nh + nt * 16 + ln][ch * 32 + quad * 8];
            }
            short8 ah = *(const short8*)&Ah[mh + ln][ch * 32 + quad * 8];
            short8 al = *(const short8*)&Al[mh + ln][ch * 32 + quad * 8];
#pragma unroll
            for (int nt = 0; nt < 4; ++nt) {
                acc[nt] = __builtin_amdgcn_mfma_f32_16x16x32_bf16(ah, bh4[nt], acc[nt], 0, 0, 0);
                acc[nt] = __builtin_amdgcn_mfma_f32_16x16x32_bf16(ah, bl4[nt], acc[nt], 0, 0, 0);
                acc[nt] = __builtin_amdgcn_mfma_f32_16x16x32_bf16(al, bh4[nt], acc[nt], 0, 0, 0);
            }
        }
    }

    const int h = (n0 + nh) >> 6;
#pragma unroll
    for (int r = 0; r < 4; ++r) {
        int m = m0 + mh + quad * 4 + r;
        int b = m >> 11, s = m & (SEQ - 1);
        size_t rowbase = ((size_t)(b * NH + h) * SEQ + s) * DHEAD;
#pragma unroll
        for (int nt = 0; nt < 4; ++nt)
            kout[rowbase + nt * 16 + ln] = f2bf(acc[nt][r]);
        float s2 = acc[0][r] * acc[0][r] + acc[1][r] * acc[1][r] +
                   acc[2][r] * acc[2][r] + acc[3][r] * acc[3][r];
#pragma unroll
        for (int off = 1; off <= 8; off <<= 1)
            s2 += __shfl_xor(s2, off);
        if (ln == 0)
            norms2[(size_t)(b * NH + h) * SEQ + s] = s2;
    }
}

// ---------------------------------------------------------------------------
// topk + gather fused, 512 threads.
// ---------------------------------------------------------------------------
__global__ __launch_bounds__(512)
void topk_gather_k(const float* __restrict__ norms2,
                   const unsigned short* __restrict__ k,
                   const unsigned short* __restrict__ v,
                   unsigned short* __restrict__ gk,
                   unsigned short* __restrict__ gvt)
{
    __shared__ unsigned long long keys[SEQ];
    __shared__ int tix[NGPAD];
    __shared__ __align__(16) unsigned short T[64][72];
    const int bh = blockIdx.x;
    const int tid = threadIdx.x;
    const float* nb = norms2 + (size_t)bh * SEQ;
    const size_t base = (size_t)bh * SEQ * DHEAD;

    for (int i = tid; i < SEQ; i += 512) {
        float nrm = sqrtf(nb[i]);
        keys[i] = ((unsigned long long)__float_as_uint(nrm) << 32) |
                  (unsigned int)(0xFFFFFFFFu - (unsigned int)i);
    }
    __syncthreads();
    for (int kk = 2; kk <= SEQ; kk <<= 1) {
        for (int j = kk >> 1; j > 0; j >>= 1) {
            for (int i = tid; i < SEQ; i += 512) {
                int ixj = i ^ j;
                if (ixj > i) {
                    unsigned long long a = keys[i], b = keys[ixj];
                    bool up = ((i & kk) == 0);
                    if ((a > b) == up) { keys[i] = b; keys[ixj] = a; }
                }
            }
            __syncthreads();
        }
    }
    if (tid < NGPAD) {
        tix[tid] = (tid < NG)
            ? (int)(0xFFFFFFFFu - (unsigned int)(keys[SEQ - 1 - tid] & 0xFFFFFFFFu))
            : 0;
    }
    __syncthreads();

    for (int t = 0; t < NGPAD / 64; ++t) {
        {
            int idx = tid;
            int row = idx >> 3, col8 = (idx & 7) << 3;
            int g = t * 64 + row;
            short8 kv = (short8)0, vv = (short8)0;
            if (g < NG) {
                int sidx = tix[g];
                kv = *(const short8*)(k + base + (size_t)sidx * DHEAD + col8);
                vv = *(const short8*)(v + base + (size_t)sidx * DHEAD + col8);
            }
            *(short8*)(gk + ((size_t)bh * NGPAD + g) * DHEAD + col8) = kv;
            *(short8*)&T[row][col8] = vv;
        }
        __syncthreads();
        {
            int idx = tid;
            int d = idx >> 3, k8 = (idx & 7) << 3;
            short8 o;
#pragma unroll
            for (int i = 0; i < 8; ++i) o[i] = (short)T[k8 + i][d];
            *(short8*)(gvt + ((size_t)bh * DHEAD + d) * NGPAD + t * 64 + k8) = o;
        }
        __syncthreads();
    }
}

// ---------------------------------------------------------------------------
// Fused attention (r6 shape, measured 91us): 512 thr, 8 waves x 16 q-rows,
// XCD-swizzled 1D grid. local flash (32 tiles) + global (4 tiles) + LN +
// MFMA gate -> fused[B,S,DMODEL] bf16.
// ---------------------------------------------------------------------------
__global__ __launch_bounds__(512)
void attn_fused_k(const unsigned short* __restrict__ qb,
                  const unsigned short* __restrict__ kb,
                  const unsigned short* __restrict__ vt,
                  const unsigned short* __restrict__ gk,
                  const unsigned short* __restrict__ gvt,
                  const unsigned short* __restrict__ Wgt,
                  const float* __restrict__ gamma,
                  const float* __restrict__ beta,
                  const float* __restrict__ bg,
                  unsigned short* __restrict__ fused)
{
    __shared__ __align__(16) unsigned short Ks[64][72];
    __shared__ __align__(16) unsigned short Vt[64][72];
    __shared__ __align__(16) unsigned short Ps[128][72];
    __shared__ __align__(16) unsigned short Wgs[64][136];
    const int flat = blockIdx.x;
    const int bh = ((flat >> 7) << 3) | (flat & 7);   // flat%8 == bh%8 (XCD)
    const int q0 = ((flat >> 3) & 15) * 128;
    const int tid = threadIdx.x;
    const int lane = tid & 63, wave = tid >> 6;
    const int quad = lane >> 4, ln = lane & 15;
    const size_t base = (size_t)bh * SEQ * DHEAD;
    const unsigned short* gkb = gk + (size_t)bh * NGPAD * DHEAD;
    const unsigned short* gvb = gvt + (size_t)bh * DHEAD * NGPAD;

    // stage Wg^T (read before first gate use; barriers in K-loop cover it)
#pragma unroll
    for (int p = 0; p < 2; ++p) {
        int idx = tid + (p << 9);
        *(short8*)&Wgs[idx >> 4][(idx & 15) << 3] = *(const short8*)(Wgt + idx * 8);
    }

    short8 qf0, qf1;
    {
        const unsigned short* qp = qb + base + (size_t)(q0 + wave * 16 + ln) * DHEAD;
        qf0 = *(const short8*)(qp + quad * 8);
        qf1 = *(const short8*)(qp + 32 + quad * 8);
    }

    f32x4 O[4], Og[4];
#pragma unroll
    for (int nt = 0; nt < 4; ++nt) {
        O[nt] = (f32x4){0.f, 0.f, 0.f, 0.f};
        Og[nt] = (f32x4){0.f, 0.f, 0.f, 0.f};
    }
    float ls[4] = {0.f, 0.f, 0.f, 0.f};
    float lg[4] = {0.f, 0.f, 0.f, 0.f};

    short8 kreg = *(const short8*)(kb + base + (size_t)(tid >> 3) * DHEAD + ((tid & 7) << 3));
    short8 vreg = *(const short8*)(vt + base + (size_t)(tid >> 3) * SEQ + ((tid & 7) << 3));
    const int srow = tid >> 3, scol8 = (tid & 7) << 3;

    // ---- local: 32 tiles ----
    for (int t = 0; t < SEQ / 64; ++t) {
        __syncthreads();
        *(short8*)&Ks[srow][scol8] = kreg;
        *(short8*)&Vt[srow][scol8] = vreg;
        __syncthreads();
        if (t + 1 < SEQ / 64) {
            kreg = *(const short8*)(kb + base + (size_t)((t + 1) * 64 + srow) * DHEAD + scol8);
            vreg = *(const short8*)(vt + base + (size_t)srow * SEQ + (t + 1) * 64 + scol8);
        } else {       // prefetch global tile 0
            kreg = *(const short8*)(gkb + (size_t)srow * DHEAD + scol8);
            vreg = *(const short8*)(gvb + (size_t)srow * NGPAD + scol8);
        }

        f32x4 s[4];
#pragma unroll
        for (int nt = 0; nt < 4; ++nt) {
            s[nt] = (f32x4){0.f, 0.f, 0.f, 0.f};
            short8 kf0 = *(const short8*)&Ks[nt * 16 + ln][quad * 8];
            short8 kf1 = *(const short8*)&Ks[nt * 16 + ln][32 + quad * 8];
            s[nt] = __builtin_amdgcn_mfma_f32_16x16x32_bf16(qf0, kf0, s[nt], 0, 0, 0);
            s[nt] = __builtin_amdgcn_mfma_f32_16x16x32_bf16(qf1, kf1, s[nt], 0, 0, 0);
        }
#pragma unroll
        for (int nt = 0; nt < 4; ++nt)
#pragma unroll
            for (int r = 0; r < 4; ++r) {
                float p = __expf(s[nt][r]);
                unsigned int us = __float_as_uint(p) >> 16;       // trunc bf16
                Ps[wave * 16 + quad * 4 + r][nt * 16 + ln] = (unsigned short)us;
                ls[r] += __uint_as_float(us << 16);               // matched
            }
#pragma unroll
        for (int ch = 0; ch < 2; ++ch) {
            short8 pf = *(const short8*)&Ps[wave * 16 + ln][ch * 32 + quad * 8];
#pragma unroll
            for (int nt = 0; nt < 4; ++nt) {
                short8 vf = *(const short8*)&Vt[nt * 16 + ln][ch * 32 + quad * 8];
                O[nt] = __builtin_amdgcn_mfma_f32_16x16x32_bf16(pf, vf, O[nt], 0, 0, 0);
            }
        }
    }

    // ---- global: 4 gathered tiles ----
    for (int t = 0; t < NGPAD / 64; ++t) {
        __syncthreads();
        *(short8*)&Ks[srow][scol8] = kreg;
        *(short8*)&Vt[srow][scol8] = vreg;
        __syncthreads();
        if (t + 1 < NGPAD / 64) {
            kreg = *(const short8*)(gkb + (size_t)((t + 1) * 64 + srow) * DHEAD + scol8);
            vreg = *(const short8*)(gvb + (size_t)srow * NGPAD + (t + 1) * 64 + scol8);
        }

        f32x4 s[4];
#pragma unroll
        for (int nt = 0; nt < 4; ++nt) {
            s[nt] = (f32x4){0.f, 0.f, 0.f, 0.f};
            short8 kf0 = *(const short8*)&Ks[nt * 16 + ln][quad * 8];
            short8 kf1 = *(const short8*)&Ks[nt * 16 + ln][32 + quad * 8];
            s[nt] = __builtin_amdgcn_mfma_f32_16x16x32_bf16(qf0, kf0, s[nt], 0, 0, 0);
            s[nt] = __builtin_amdgcn_mfma_f32_16x16x32_bf16(qf1, kf1, s[nt], 0, 0, 0);
        }
#pragma unroll
        for (int nt = 0; nt < 4; ++nt) {
            bool valid = (t * 64 + nt * 16 + ln) < NG;
#pragma unroll
            for (int r = 0; r < 4; ++r) {
                float p = valid ? __expf(s[nt][r]) : 0.f;
                unsigned int us = __float_as_uint(p) >> 16;
                Ps[wave * 16 + quad * 4 + r][nt * 16 + ln] = (unsigned short)us;
                lg[r] += __uint_as_float(us << 16);
            }
        }
#pragma unroll
        for (int ch = 0; ch < 2; ++ch) {
            short8 pf = *(const short8*)&Ps[wave * 16 + ln][ch * 32 + quad * 8];
#pragma unroll
            for (int nt = 0; nt < 4; ++nt) {
                short8 vf = *(const short8*)&Vt[nt * 16 + ln][ch * 32 + quad * 8];
                Og[nt] = __builtin_amdgcn_mfma_f32_16x16x32_bf16(pf, vf, Og[nt], 0, 0, 0);
            }
        }
    }

    // ---- reductions ----
#pragma unroll
    for (int off = 1; off <= 8; off <<= 1)
#pragma unroll
        for (int r = 0; r < 4; ++r) {
            ls[r] += __shfl_xor(ls[r], off);
            lg[r] += __shfl_xor(lg[r], off);
        }
    float invl[4];
#pragma unroll
    for (int r = 0; r < 4; ++r) invl[r] = 1.f / ls[r];

    // ---- layernorm(global) ----
    float xs[4][4];
#pragma unroll
    for (int r = 0; r < 4; ++r) {
        float inv = 1.f / lg[r];
#pragma unroll
        for (int nt = 0; nt < 4; ++nt) xs[nt][r] = Og[nt][r] * inv;
    }
    float mu[4], rsd[4];
#pragma unroll
    for (int r = 0; r < 4; ++r) {
        float sm = xs[0][r] + xs[1][r] + xs[2][r] + xs[3][r];
#pragma unroll
        for (int off = 1; off <= 8; off <<= 1) sm += __shfl_xor(sm, off);
        mu[r] = sm * (1.f / 64.f);
    }
#pragma unroll
    for (int r = 0; r < 4; ++r) {
        float sv = 0.f;
#pragma unroll
        for (int nt = 0; nt < 4; ++nt) {
            float d = xs[nt][r] - mu[r];
            sv += d * d;
        }
#pragma unroll
        for (int off = 1; off <= 8; off <<= 1) sv += __shfl_xor(sv, off);
        rsd[r] = rsqrtf(sv * (1.f / 64.f) + LNEPS);
    }
#pragma unroll
    for (int nt = 0; nt < 4; ++nt) {
        float g = gamma[nt * 16 + ln], bb = beta[nt * 16 + ln];
#pragma unroll
        for (int r = 0; r < 4; ++r)
            xs[nt][r] = (xs[nt][r] - mu[r]) * rsd[r] * g + bb;
    }

    // ---- gate via MFMA (2 passes through Ps; intra-wave rows, no barrier) --
    float lf[4][4];
#pragma unroll
    for (int nt = 0; nt < 4; ++nt)
#pragma unroll
        for (int r = 0; r < 4; ++r) {
            lf[nt][r] = O[nt][r] * invl[r];
            Ps[wave * 16 + quad * 4 + r][nt * 16 + ln] = f2bf(lf[nt][r]);
        }
    f32x4 gacc[4];
#pragma unroll
    for (int ng = 0; ng < 4; ++ng) {
        float bgv = bg[ng * 16 + ln];
        gacc[ng] = (f32x4){bgv, bgv, bgv, bgv};
    }
#pragma unroll
    for (int ch = 0; ch < 2; ++ch) {
        short8 af = *(const short8*)&Ps[wave * 16 + ln][ch * 32 + quad * 8];
#pragma unroll
        for (int ng = 0; ng < 4; ++ng) {
            short8 bf = *(const short8*)&Wgs[ng * 16 + ln][ch * 32 + quad * 8];
            gacc[ng] = __builtin_amdgcn_mfma_f32_16x16x32_bf16(af, bf, gacc[ng], 0, 0, 0);
        }
    }
#pragma unroll
    for (int nt = 0; nt < 4; ++nt)
#pragma unroll
        for (int r = 0; r < 4; ++r)
            Ps[wave * 16 + quad * 4 + r][nt * 16 + ln] = f2bf(xs[nt][r]);
#pragma unroll
    for (int ch = 0; ch < 2; ++ch) {
        short8 af = *(const short8*)&Ps[wave * 16 + ln][ch * 32 + quad * 8];
#pragma unroll
        for (int ng = 0; ng < 4; ++ng) {
            short8 bf = *(const short8*)&Wgs[ng * 16 + ln][64 + ch * 32 + quad * 8];
            gacc[ng] = __builtin_amdgcn_mfma_f32_16x16x32_bf16(af, bf, gacc[ng], 0, 0, 0);
        }
    }

    // ---- fuse + store ----
    const int b = bh >> 4, h = bh & 15;
#pragma unroll
    for (int ng = 0; ng < 4; ++ng)
#pragma unroll
        for (int r = 0; r < 4; ++r) {
            float gt = 1.f / (1.f + __expf(-gacc[ng][r]));
            float f = gt * lf[ng][r] + (1.f - gt) * xs[ng][r];
            int s = q0 + wave * 16 + quad * 4 + r;
            fused[((size_t)(b * SEQ + s)) * DMODEL + h * DHEAD + ng * 16 + ln] = f2bf(f);
        }
}

// ---------------------------------------------------------------------------
extern "C" void kernel_launch(void* const* d_in, const int* in_sizes, int n_in,
                              void* d_out, int out_size, void* d_ws, size_t ws_size,
                              hipStream_t stream)
{
    (void)in_sizes; (void)n_in; (void)out_size; (void)ws_size;
    const float* x    = (const float*)d_in[0];
    const float* Wq   = (const float*)d_in[1];
    const float* Wk   = (const float*)d_in[2];
    const float* Wv   = (const float*)d_in[3];
    const float* Wo   = (const float*)d_in[4];
    const float* bo   = (const float*)d_in[5];
    const float* ln_g = (const float*)d_in[6];
    const float* ln_b = (const float*)d_in[7];
    const float* Wg   = (const float*)d_in[8];
    const float* bg   = (const float*)d_in[9];

    char* w = (char*)d_ws;
    const size_t MB = 1024ull * 1024ull;
    unsigned short* kb16  = (unsigned short*)(w);
    unsigned short* qb16  = (unsigned short*)(w + 8 * MB);
    unsigned short* vb16  = (unsigned short*)(w + 16 * MB);
    unsigned short* vt16  = (unsigned short*)(w + 24 * MB);
    unsigned short* xh    = (unsigned short*)(w + 32 * MB);
    unsigned short* xl    = (unsigned short*)(w + 40 * MB);
    unsigned short* Wqt   = (unsigned short*)(w + 48 * MB);
    unsigned short* Wvt   = (unsigned short*)(w + 50 * MB);   // contiguous after Wqt
    unsigned short* Wot   = (unsigned short*)(w + 52 * MB);
    unsigned short* Wkh   = (unsigned short*)(w + 54 * MB);
    unsigned short* Wkl   = (unsigned short*)(w + 56 * MB);
    unsigned short* Wgt   = (unsigned short*)(w + 58 * MB);
    float*          norms2= (float*)(w + 59 * MB);
    unsigned short* gk16  = (unsigned short*)(w + 60 * MB);
    unsigned short* gvt16 = (unsigned short*)(w + 61 * MB);
    unsigned short* fusedb = xh;   // xh dead after projections

    const int M = 4096, N = 1024, K = 1024;

    prep_k<<<3073, 256, 0, stream>>>(x, Wq, Wv, Wo, Wk, Wg,
                                     xh, xl, Wqt, Wvt, Wot, Wkh, Wkl, Wgt);

    dim3 gqv(2048 / 128, M / 128);
    gemm_bf16_k<<<gqv, 512, 0, stream>>>(xh, Wqt, nullptr, qb16, vb16, vt16,
                                         M, 2048, K, 3);

    dim3 gkp(N / 128, M / 64);
    gemm_kproj_mfma<<<gkp, 512, 0, stream>>>(xh, xl, Wkh, Wkl, kb16, norms2);

    topk_gather_k<<<BHT, 512, 0, stream>>>(norms2, kb16, vb16, gk16, gvt16);

    attn_fused_k<<<512, 512, 0, stream>>>(qb16, kb16, vt16, gk16, gvt16, Wgt,
                                          ln_g, ln_b, bg, fusedb);

    dim3 go_(N / 128, M / 128);
    gemm_bf16_k<<<go_, 512, 0, stream>>>(fusedb, Wot, bo, (float*)d_out, nullptr,
                                         nullptr, M, N, K, 0);
}